// Round 1
// baseline (139.777 us; speedup 1.0000x reference)
//
#include <hip/hip_runtime.h>

// Forbid FMA contraction EVERYWHERE: the fallback path recomputes distances
// and must be bit-identical to the main loop AND to numpy's unfused
// ((dx*dx + dy*dy) + dz*dz).
#pragma clang fp contract(off)

typedef unsigned long long u64;
typedef unsigned int u32;

#define BB 8
#define LL 2048
#define MM 4096
#define KK 25
#define WPB 16           // waves per block
#define QPW 2            // queries per wave (shared LDS candidate stream)
#define TPB 1024
#define SENT 0xFFFFFFFFFFFFFFFFull

// Wave64 min-reduce -> wave-uniform scalar (proven round-9 DPP ladder).
static __device__ __forceinline__ u32 wave_min_u32(u32 x) {
    u32 t;
    t = (u32)__builtin_amdgcn_update_dpp(0, (int)x, 0xB1, 0xF, 0xF, true);   // xor1
    x = t < x ? t : x;
    t = (u32)__builtin_amdgcn_update_dpp(0, (int)x, 0x4E, 0xF, 0xF, true);   // xor2
    x = t < x ? t : x;
    t = (u32)__builtin_amdgcn_update_dpp(0, (int)x, 0x141, 0xF, 0xF, true);  // half-row mirror
    x = t < x ? t : x;
    t = (u32)__builtin_amdgcn_update_dpp(0, (int)x, 0x140, 0xF, 0xF, true);  // row mirror
    x = t < x ? t : x;
    t = (u32)__builtin_amdgcn_update_dpp((int)x, (int)x, 0x142, 0xF, 0xF, false); // row_bcast15
    x = t < x ? t : x;
    t = (u32)__builtin_amdgcn_update_dpp((int)x, (int)x, 0x143, 0xF, 0xF, false); // row_bcast31
    x = t < x ? t : x;
    return (u32)__builtin_amdgcn_readlane((int)x, 63);
}

// ROUND 12: dual-query waves (2 queries share each candidate ds_read ->
// LDS traffic/query halved), min/med3 value cascade + v_perm byte-packed
// index list (19 VALU/cand/query vs 28), top-3/lane (exact-rescan fallback
// absorbs the rarer exhaustion), masked candidates poisoned (x=3e30 ->
// dsq=inf, fminf(inf,1000)=1000.0f exact); epilogue coords re-gathered
// from global Y since sP.x is poisoned. Extraction phase verbatim round-9.
__global__ void __launch_bounds__(TPB, 8) knn_kernel(
    const float* __restrict__ CB, const float* __restrict__ maskA,
    const float* __restrict__ Y, const int* __restrict__ Yt,
    const int* __restrict__ Ym, float* __restrict__ out)
{
    // {x_or_poison, y, z, wmask}; wmask = +inf (valid) or 1000.0f (masked).
    __shared__ float4 sP[MM];   // 64 KiB -> 2 blocks/CU

    const int tid  = threadIdx.x;
    const int lane = tid & 63;
    const int wv   = tid >> 6;
    const int blk  = blockIdx.x;
    const int b    = blk >> 6;        // 64 blocks per batch (LL/(WPB*QPW))
    const int qg   = blk & 63;

    const float* Yb  = Y  + (size_t)b * MM * 3;
    const int*   Ymb = Ym + (size_t)b * MM;
    const int*   Ytb = Yt + (size_t)b * MM;

    for (int p = tid; p < MM; p += TPB) {
        const float x = Yb[3 * p + 0];
        const float y = Yb[3 * p + 1];
        const float z = Yb[3 * p + 2];
        const bool valid = Ymb[p] != 0;
        float4 v;
        v.x = valid ? x : 3.0e30f;            // poison: dsq overflows to +inf
        v.y = y;
        v.z = z;
        v.w = valid ? __builtin_inff() : 1000.0f;
        sP[p] = v;
    }
    __syncthreads();

    const int lA = qg * (WPB * QPW) + (wv << 1);
    const int qA = b * LL + lA;
    const int qB = qA + 1;

    float* out_y = out;                                   // [B,L,K,3]
    float* out_t = out + (size_t)BB * LL * KK * 3;        // [B,L,K]
    float* out_m = out_t + (size_t)BB * LL * KK;          // [B,L,K]
    float* out_d = out_m + (size_t)BB * LL * KK;          // [B,L]

    // masked query => every value exactly 1000.0, ties resolve to indices
    // 0..24 (verified rounds 2/4/5/8/9). Coords from global (sP.x poisoned).
    auto fastout = [&](int q) {
        if (lane < KK) {
            const int p = lane;
            const size_t o = (size_t)q * KK + lane;
            out_y[3 * o + 0] = Yb[3 * p + 0];
            out_y[3 * o + 1] = Yb[3 * p + 1];
            out_y[3 * o + 2] = Yb[3 * p + 2];
            out_t[o] = (float)Ytb[p];
            out_m[o] = (float)Ymb[p];
            if (lane == 0) out_d[q] = sqrtf(1000.0f);
        }
    };

    const bool liveA = maskA[qA] != 0.0f;
    const bool liveB = maskA[qB] != 0.0f;
    if (!liveA) fastout(qA);
    if (!liveB) fastout(qB);
    if (!liveA && !liveB) return;

    float cAx = CB[3 * qA + 0], cAy = CB[3 * qA + 1], cAz = CB[3 * qA + 2];
    float cBx = CB[3 * qB + 0], cBy = CB[3 * qB + 1], cBz = CB[3 * qB + 2];
    // mirror the live query into the dead slot; dead slot is never extracted
    if (!liveA) { cAx = cBx; cAy = cBy; cAz = cBz; }
    if (!liveB) { cBx = cAx; cBy = cAy; cBz = cAz; }

    // per-lane stable top-3 (ascending by (v, j)); indices byte-packed in J:
    // byte0=j1, byte1=j2, byte2=j3. v_perm selectors (sel 0-3 -> src1=jnew,
    // 4-7 -> src0=J): insert at pos1/2/3.
    float vA1 = 3.0e38f, vA2 = 3.0e38f, vA3 = 3.0e38f;
    float vB1 = 3.0e38f, vB2 = 3.0e38f, vB3 = 3.0e38f;
    u32 JA = 0u, JB = 0u;
    const u32 SEL1 = 0x06050400u;   // (j, j1, j2, -)
    const u32 SEL2 = 0x06050004u;   // (j1, j, j2, -)
    const u32 SEL3 = 0x06000504u;   // (j1, j2, j, -)

#pragma unroll 8
    for (int j = 0; j < 64; ++j) {
        const float4 c = sP[(j << 6) | lane];

        float dx = cAx - c.x, dy = cAy - c.y, dz = cAz - c.z;
        float dsq = (dx * dx + dy * dy) + dz * dz;
        const float vA = fminf(dsq, c.w);   // masked: min(inf,1000)=1000 exact
        dx = cBx - c.x; dy = cBy - c.y; dz = cBz - c.z;
        dsq = (dx * dx + dy * dy) + dz * dz;
        const float vB = fminf(dsq, c.w);

        {
            const bool a1 = vA < vA1, a2 = vA < vA2, a3 = vA < vA3;
            const u32 sa = a1 ? SEL1 : (a2 ? SEL2 : SEL3);
            const u32 Jp = __builtin_amdgcn_perm(JA, (u32)j, sa);
            const float n2 = __builtin_amdgcn_fmed3f(vA, vA1, vA2);
            const float n3 = __builtin_amdgcn_fmed3f(vA, vA2, vA3);
            vA1 = fminf(vA, vA1);
            vA2 = n2; vA3 = n3;
            JA = a3 ? Jp : JA;
        }
        {
            const bool b1 = vB < vB1, b2 = vB < vB2, b3 = vB < vB3;
            const u32 sb = b1 ? SEL1 : (b2 ? SEL2 : SEL3);
            const u32 Jp = __builtin_amdgcn_perm(JB, (u32)j, sb);
            const float n2 = __builtin_amdgcn_fmed3f(vB, vB1, vB2);
            const float n3 = __builtin_amdgcn_fmed3f(vB, vB2, vB3);
            vB1 = fminf(vB, vB1);
            vB2 = n2; vB3 = n3;
            JB = b3 ? Jp : JB;
        }
    }

    // keys: (value_bits + 1) << 32 | p — monotone in (value, index), unique.
    // Extraction phase is the verified round-9 structure, per live query.
    auto tail = [&](float v1, float v2, float v3, u32 J,
                    float cx, float cy, float cz, int q) {
        auto distv = [&](int j) -> float {
            const float4 c = sP[(j << 6) | lane];
            const float dx = cx - c.x, dy = cy - c.y, dz = cz - c.z;
            const float dsq = (dx * dx + dy * dy) + dz * dz;
            return fminf(dsq, c.w);
        };
        u64 k1 = ((u64)(__float_as_uint(v1) + 1u) << 32) | (u32)((( J        & 0xFFu) << 6) | lane);
        u64 k2 = ((u64)(__float_as_uint(v2) + 1u) << 32) | (u32)((((J >> 8)  & 0xFFu) << 6) | lane);
        u64 k3 = ((u64)(__float_as_uint(v3) + 1u) << 32) | (u32)((((J >> 16) & 0xFFu) << 6) | lane);
        u64 k4 = SENT;
        u64 lastpop = 0;
        u64 mykey = 0;
#pragma unroll 1
        for (int it = 0; it < KK; ++it) {
            const bool need = (k1 == SENT);
            if (__any(need)) {             // lane consumed its 3: exact rescan
                u64 found = SENT;
#pragma unroll 8
                for (int j = 0; j < 64; ++j) {
                    const float v = distv(j);
                    const u64 key = ((u64)(__float_as_uint(v) + 1u) << 32)
                                  | (u32)((j << 6) | lane);
                    if (key > lastpop && key < found) found = key;
                }
                if (need) k1 = found;
            }
            const u32 vh = (u32)(k1 >> 32);
            const u32 vl = (u32)k1;
            const u32 bv = wave_min_u32(vh);
            const u64 ball = __ballot(vh == bv);
            u32 bp;
            if (__popcll(ball) == 1) {        // ~always taken
                const int wl = __ffsll((unsigned long long)ball) - 1;
                bp = (u32)__builtin_amdgcn_readlane((int)vl, wl);
            } else {                          // exact value tie: min index wins
                u32 cp = (vh == bv) ? vl : 0xFFFFFFFFu;
#pragma unroll
                for (int off = 32; off; off >>= 1) {
                    const u32 o = __shfl_xor(cp, off, 64);
                    cp = (o < cp) ? o : cp;
                }
                bp = cp;
            }
            if (lane == it) mykey = ((u64)bv << 32) | bp;
            if (vh == bv && vl == bp) {       // unique keys -> exactly one winner
                lastpop = k1;
                k1 = k2; k2 = k3; k3 = k4; k4 = SENT;
            }
        }
        if (lane < KK) {
            const int p   = (int)(mykey & 0xFFFFFFFFull);
            const float v = __uint_as_float((u32)(mykey >> 32) - 1u);
            const size_t o = (size_t)q * KK + lane;
            out_y[3 * o + 0] = Yb[3 * p + 0];   // global: sP.x is poisoned
            out_y[3 * o + 1] = Yb[3 * p + 1];
            out_y[3 * o + 2] = Yb[3 * p + 2];
            out_t[o] = (float)Ytb[p];
            out_m[o] = (float)Ymb[p];
            if (lane == 0) out_d[q] = sqrtf(v);
        }
    };

    if (liveA) tail(vA1, vA2, vA3, JA, cAx, cAy, cAz, qA);
    if (liveB) tail(vB1, vB2, vB3, JB, cBx, cBy, cBz, qB);
}

extern "C" void kernel_launch(void* const* d_in, const int* in_sizes, int n_in,
                              void* d_out, int out_size, void* d_ws, size_t ws_size,
                              hipStream_t stream) {
    const float* CB   = (const float*)d_in[0];
    const float* mask = (const float*)d_in[1];
    const float* Y    = (const float*)d_in[2];
    const int*   Yt   = (const int*)d_in[3];
    const int*   Ym   = (const int*)d_in[4];
    float* out = (float*)d_out;

    dim3 grid(BB * LL / (WPB * QPW));   // 512 blocks = one full residency round
    dim3 block(TPB);
    hipLaunchKernelGGL(knn_kernel, grid, block, 0, stream, CB, mask, Y, Yt, Ym, out);
}